// Round 1
// baseline (356.011 us; speedup 1.0000x reference)
//
#include <hip/hip_runtime.h>
#include <hip/hip_bf16.h>
#include <math.h>

#define B_   4
#define S_   2048
#define DIN  1024
#define DATT 1024
#define DHID 1024

typedef short bf16x8 __attribute__((ext_vector_type(8)));
typedef float f32x4  __attribute__((ext_vector_type(4)));

__device__ inline unsigned short f2bf(float f) {
    unsigned u = __float_as_uint(f);
    u += 0x7fffu + ((u >> 16) & 1u);
    return (unsigned short)(u >> 16);
}

// AMODE: 0 = A fp32 row-major (convert to bf16 while staging), 1 = A bf16 row-major
// BMODE: 0 = B fp32 [K][N] (transpose-stage), 1 = B bf16 [N][K] (row-direct), 2 = B bf16 [K][N] (transpose-stage)
// EPI:   0 = bf16 out (+bias), 1 = bf16 gelu(x+bias), 2 = fp32 out scale + mask*(-1e9), 3 = fp32 out
template<int AMODE, int BMODE, int EPI>
__global__ __launch_bounds__(256)
void gemm_k(const void* __restrict__ Ap, const void* __restrict__ Bp,
            const float* __restrict__ bias, const int* __restrict__ maskp,
            void* __restrict__ Cp,
            int M, int N, int K, int lda, int ldb, int ldc,
            long aStride, long bStride, long cStride, long mStride,
            float scale)
{
    __shared__ __align__(16) unsigned short Al[128][40];
    __shared__ __align__(16) unsigned short Bl[128][40];

    const int tid  = threadIdx.x;
    const int z    = blockIdx.z;
    const int row0 = blockIdx.y * 128;
    const int col0 = blockIdx.x * 128;

    const int wave = tid >> 6, lane = tid & 63;
    const int lr = lane & 15, lg = lane >> 4;
    const int wm = (wave >> 1) * 64, wn = (wave & 1) * 64;

    f32x4 acc[4][4] = {};

    for (int k0 = 0; k0 < K; k0 += 32) {
        // ---- stage A tile [128][32] ----
        if (AMODE == 0) {
            const float* A = (const float*)Ap + (size_t)aStride * z;
            int r = tid >> 3, kc = (tid & 7) * 4;
#pragma unroll
            for (int q = 0; q < 4; ++q) {
                int row = q * 32 + r;
                float4 v = *(const float4*)(A + (size_t)(row0 + row) * lda + k0 + kc);
                unsigned a0 = (unsigned)f2bf(v.x) | ((unsigned)f2bf(v.y) << 16);
                unsigned a1 = (unsigned)f2bf(v.z) | ((unsigned)f2bf(v.w) << 16);
                *(uint2*)&Al[row][kc] = make_uint2(a0, a1);
            }
        } else {
            const unsigned short* A = (const unsigned short*)Ap + (size_t)aStride * z;
#pragma unroll
            for (int p = 0; p < 2; ++p) {
                int c = p * 256 + tid;
                int row = c >> 2, kc = (c & 3) * 8;
                *(uint4*)&Al[row][kc] = *(const uint4*)(A + (size_t)(row0 + row) * lda + k0 + kc);
            }
        }
        // ---- stage B tile as Bl[n][k] ----
        if (BMODE == 1) {
            const unsigned short* Bn = (const unsigned short*)Bp + (size_t)bStride * z;
#pragma unroll
            for (int p = 0; p < 2; ++p) {
                int c = p * 256 + tid;
                int n = c >> 2, kc = (c & 3) * 8;
                *(uint4*)&Bl[n][kc] = *(const uint4*)(Bn + (size_t)(col0 + n) * ldb + k0 + kc);
            }
        } else if (BMODE == 0) {
            const float* Bf = (const float*)Bp + (size_t)bStride * z;
            int n = tid & 127, h = tid >> 7;
#pragma unroll
            for (int g = 0; g < 4; ++g) {
                int kb = (h + 2 * g) * 4;
                float v0 = Bf[(size_t)(k0 + kb + 0) * ldb + col0 + n];
                float v1 = Bf[(size_t)(k0 + kb + 1) * ldb + col0 + n];
                float v2 = Bf[(size_t)(k0 + kb + 2) * ldb + col0 + n];
                float v3 = Bf[(size_t)(k0 + kb + 3) * ldb + col0 + n];
                unsigned a0 = (unsigned)f2bf(v0) | ((unsigned)f2bf(v1) << 16);
                unsigned a1 = (unsigned)f2bf(v2) | ((unsigned)f2bf(v3) << 16);
                *(uint2*)&Bl[n][kb] = make_uint2(a0, a1);
            }
        } else { // BMODE == 2
            const unsigned short* Bh = (const unsigned short*)Bp + (size_t)bStride * z;
            int n = tid & 127, h = tid >> 7;
#pragma unroll
            for (int g = 0; g < 4; ++g) {
                int kb = (h + 2 * g) * 4;
                unsigned short v0 = Bh[(size_t)(k0 + kb + 0) * ldb + col0 + n];
                unsigned short v1 = Bh[(size_t)(k0 + kb + 1) * ldb + col0 + n];
                unsigned short v2 = Bh[(size_t)(k0 + kb + 2) * ldb + col0 + n];
                unsigned short v3 = Bh[(size_t)(k0 + kb + 3) * ldb + col0 + n];
                unsigned a0 = (unsigned)v0 | ((unsigned)v1 << 16);
                unsigned a1 = (unsigned)v2 | ((unsigned)v3 << 16);
                *(uint2*)&Bl[n][kb] = make_uint2(a0, a1);
            }
        }
        __syncthreads();

        bf16x8 af[4], bfr[4];
#pragma unroll
        for (int i = 0; i < 4; ++i) af[i]  = *(const bf16x8*)&Al[wm + i * 16 + lr][lg * 8];
#pragma unroll
        for (int i = 0; i < 4; ++i) bfr[i] = *(const bf16x8*)&Bl[wn + i * 16 + lr][lg * 8];
#pragma unroll
        for (int mi = 0; mi < 4; ++mi)
#pragma unroll
            for (int ni = 0; ni < 4; ++ni)
                acc[mi][ni] = __builtin_amdgcn_mfma_f32_16x16x32_bf16(af[mi], bfr[ni], acc[mi][ni], 0, 0, 0);
        __syncthreads();
    }

    // ---- epilogue ----
    if (EPI <= 1) {
        unsigned short* C = (unsigned short*)Cp + (size_t)cStride * z;
#pragma unroll
        for (int mi = 0; mi < 4; ++mi)
#pragma unroll
            for (int ni = 0; ni < 4; ++ni)
#pragma unroll
                for (int v = 0; v < 4; ++v) {
                    int row = row0 + wm + mi * 16 + lg * 4 + v;
                    int col = col0 + wn + ni * 16 + lr;
                    float val = acc[mi][ni][v] + bias[col];
                    if (EPI == 1) val = 0.5f * val * (1.0f + erff(val * 0.70710678118654752f));
                    C[(size_t)row * ldc + col] = f2bf(val);
                }
    } else {
        float* C = (float*)Cp + (size_t)cStride * z;
        const int* mp = (EPI == 2) ? (maskp + (size_t)mStride * z) : nullptr;
#pragma unroll
        for (int mi = 0; mi < 4; ++mi)
#pragma unroll
            for (int ni = 0; ni < 4; ++ni)
#pragma unroll
                for (int v = 0; v < 4; ++v) {
                    int row = row0 + wm + mi * 16 + lg * 4 + v;
                    int col = col0 + wn + ni * 16 + lr;
                    float val = acc[mi][ni][v];
                    if (EPI == 2) val = val * scale + (float)mp[(size_t)row * ldc + col] * (-1e9f);
                    C[(size_t)row * ldc + col] = val;
                }
    }
}

// row softmax in place: one block per row of 2048 fp32
__global__ __launch_bounds__(256)
void softmax_k(float* __restrict__ attn)
{
    const int row = blockIdx.x;
    float* p = attn + (size_t)row * S_;
    const int tid = threadIdx.x;

    float4 a = ((const float4*)p)[tid * 2];
    float4 b = ((const float4*)p)[tid * 2 + 1];

    float m = fmaxf(fmaxf(fmaxf(a.x, a.y), fmaxf(a.z, a.w)),
                    fmaxf(fmaxf(b.x, b.y), fmaxf(b.z, b.w)));
#pragma unroll
    for (int o = 32; o; o >>= 1) m = fmaxf(m, __shfl_xor(m, o));

    __shared__ float redm[4];
    __shared__ float reds[4];
    if ((tid & 63) == 0) redm[tid >> 6] = m;
    __syncthreads();
    m = fmaxf(fmaxf(redm[0], redm[1]), fmaxf(redm[2], redm[3]));

    float e[8];
    e[0] = expf(a.x - m); e[1] = expf(a.y - m); e[2] = expf(a.z - m); e[3] = expf(a.w - m);
    e[4] = expf(b.x - m); e[5] = expf(b.y - m); e[6] = expf(b.z - m); e[7] = expf(b.w - m);
    float s = e[0] + e[1] + e[2] + e[3] + e[4] + e[5] + e[6] + e[7];
#pragma unroll
    for (int o = 32; o; o >>= 1) s += __shfl_xor(s, o);
    if ((tid & 63) == 0) reds[tid >> 6] = s;
    __syncthreads();
    s = reds[0] + reds[1] + reds[2] + reds[3];
    float inv = 1.0f / s;

    float4 oa = make_float4(e[0] * inv, e[1] * inv, e[2] * inv, e[3] * inv);
    float4 ob = make_float4(e[4] * inv, e[5] * inv, e[6] * inv, e[7] * inv);
    ((float4*)p)[tid * 2]     = oa;
    ((float4*)p)[tid * 2 + 1] = ob;
}

extern "C" void kernel_launch(void* const* d_in, const int* in_sizes, int n_in,
                              void* d_out, int out_size, void* d_ws, size_t ws_size,
                              hipStream_t stream)
{
    const float* x    = (const float*)d_in[0];   // [B,S,DIN]
    const int*   mask = (const int*)d_in[1];     // [B,S,S]
    const float* Wq   = (const float*)d_in[2];
    const float* bq   = (const float*)d_in[3];
    const float* Wk   = (const float*)d_in[4];
    const float* bk   = (const float*)d_in[5];
    const float* Wv   = (const float*)d_in[6];
    const float* bv   = (const float*)d_in[7];

    float* ctx  = (float*)d_out;                           // [B,S,DHID] fp32 (written last)
    float* attn = ctx + (size_t)B_ * S_ * DHID;            // [B,S,S] fp32

    // scratch: Qb,Kb (bf16) live in the (not-yet-needed) context region; WV bf16 in d_ws
    unsigned short* Qb  = (unsigned short*)ctx;                  // 16.78 MB
    unsigned short* Kb  = Qb + (size_t)B_ * S_ * DATT;           // 16.78 MB
    unsigned short* WVb = (unsigned short*)d_ws;                 // 16.78 MB

    dim3 blk(256);
    const int MS = B_ * S_;  // 8192

    // Q = X @ Wq + bq  -> bf16
    gemm_k<0, 0, 0><<<dim3(DATT / 128, MS / 128, 1), blk, 0, stream>>>(
        x, Wq, bq, nullptr, Qb, MS, DATT, DIN, DIN, DATT, DATT, 0, 0, 0, 0, 1.0f);
    // K = X @ Wk + bk  -> bf16
    gemm_k<0, 0, 0><<<dim3(DATT / 128, MS / 128, 1), blk, 0, stream>>>(
        x, Wk, bk, nullptr, Kb, MS, DATT, DIN, DIN, DATT, DATT, 0, 0, 0, 0, 1.0f);
    // WV = gelu(X @ Wv + bv) -> bf16
    gemm_k<0, 0, 1><<<dim3(DHID / 128, MS / 128, 1), blk, 0, stream>>>(
        x, Wv, bv, nullptr, WVb, MS, DHID, DIN, DIN, DHID, DHID, 0, 0, 0, 0, 1.0f);
    // scores = Q @ K^T / 32 + mask*(-1e9) -> fp32 into attn region
    gemm_k<1, 1, 2><<<dim3(S_ / 128, S_ / 128, B_), blk, 0, stream>>>(
        Qb, Kb, nullptr, mask, attn, S_, S_, DATT, DATT, DATT, S_,
        (long)S_ * DATT, (long)S_ * DATT, (long)S_ * S_, (long)S_ * S_, 0.03125f);
    // softmax rows in place
    softmax_k<<<dim3(B_ * S_), blk, 0, stream>>>(attn);
    // context = attn @ WV -> fp32 (overwrites Qb/Kb region, no longer read)
    gemm_k<0, 2, 3><<<dim3(DHID / 128, S_ / 128, B_), blk, 0, stream>>>(
        attn, WVb, nullptr, nullptr, ctx, S_, DHID, S_, S_, DHID, DHID,
        (long)S_ * S_, (long)S_ * DHID, (long)S_ * DHID, 0, 1.0f);
}

// Round 2
// 265.790 us; speedup vs baseline: 1.3394x; 1.3394x over previous
//
#include <hip/hip_runtime.h>
#include <hip/hip_bf16.h>
#include <math.h>

#define B_   4
#define S_   2048
#define DIN  1024
#define DATT 1024
#define DHID 1024

typedef short bf16x8 __attribute__((ext_vector_type(8)));
typedef float f32x4  __attribute__((ext_vector_type(4)));

__device__ inline unsigned short f2bf(float f) {
    unsigned u = __float_as_uint(f);
    u += 0x7fffu + ((u >> 16) & 1u);
    return (unsigned short)(u >> 16);
}

__device__ inline void gld16(const void* g, void* l) {
    __builtin_amdgcn_global_load_lds(
        (const __attribute__((address_space(1))) unsigned int*)g,
        (__attribute__((address_space(3))) unsigned int*)l, 16, 0, 0);
}

// ---------------- prep: X fp32 -> bf16 ----------------
__global__ __launch_bounds__(256)
void xcvt_k(const float* __restrict__ x, unsigned short* __restrict__ xb)
{
    int i = blockIdx.x * 256 + threadIdx.x;       // 1,048,576 threads, 8 elems each
    const float4* p = (const float4*)x + (size_t)i * 2;
    float4 v0 = p[0], v1 = p[1];
    uint4 o;
    o.x = (unsigned)f2bf(v0.x) | ((unsigned)f2bf(v0.y) << 16);
    o.y = (unsigned)f2bf(v0.z) | ((unsigned)f2bf(v0.w) << 16);
    o.z = (unsigned)f2bf(v1.x) | ((unsigned)f2bf(v1.y) << 16);
    o.w = (unsigned)f2bf(v1.z) | ((unsigned)f2bf(v1.w) << 16);
    ((uint4*)xb)[i] = o;
}

// ---------------- prep: W [K][N] fp32 -> Wt [N][K] bf16 (gather; L2 absorbs) ----------------
__global__ __launch_bounds__(256)
void wcvt_k(const float* __restrict__ Wq, const float* __restrict__ Wk,
            const float* __restrict__ Wv, unsigned short* __restrict__ Wt)
{
    int w = blockIdx.y;
    const float* W = (w == 0) ? Wq : ((w == 1) ? Wk : Wv);
    unsigned short* D = Wt + (size_t)w * DIN * DATT;
    int t = blockIdx.x * 256 + threadIdx.x;       // 65536 threads per weight
    int n  = t >> 6;
    int kc = (t & 63) * 16;
    unsigned short r[16];
#pragma unroll
    for (int i = 0; i < 16; ++i) r[i] = f2bf(W[(size_t)(kc + i) * DATT + n]);
    uint4 o0, o1;
    o0.x = (unsigned)r[0] | ((unsigned)r[1] << 16);  o0.y = (unsigned)r[2] | ((unsigned)r[3] << 16);
    o0.z = (unsigned)r[4] | ((unsigned)r[5] << 16);  o0.w = (unsigned)r[6] | ((unsigned)r[7] << 16);
    o1.x = (unsigned)r[8] | ((unsigned)r[9] << 16);  o1.y = (unsigned)r[10] | ((unsigned)r[11] << 16);
    o1.z = (unsigned)r[12] | ((unsigned)r[13] << 16); o1.w = (unsigned)r[14] | ((unsigned)r[15] << 16);
    *(uint4*)(D + (size_t)n * DIN + kc)     = o0;
    *(uint4*)(D + (size_t)n * DIN + kc + 8) = o1;
}

// ---------------- GEMM: 128x128 tile, BK=64, global_load_lds + XOR swizzle ----------------
// AMODE: 0 = A bf16 row-major via global_load_lds; 1 = A fp32 cvt reg-staged (swizzled ds_write)
// EPI:   0 = bf16 out +bias; 1 = bf16 gelu(x+bias) TRANSPOSED out ([DHID][S] per batch);
//        2 = fp32 out scale + mask*(-1e9); 3 = fp32 out
template<int AMODE, int EPI>
__global__ __launch_bounds__(256)
void gemm_k(const void* __restrict__ Ap, const unsigned short* __restrict__ Bp,
            const float* __restrict__ bias, const int* __restrict__ maskp,
            void* __restrict__ Cp, int K, int lda, int ldb, int ldc,
            long aStride, long bStride, long cStride, long mStride, float scale)
{
    __shared__ __align__(16) unsigned short sh[2][128][64];   // 32 KB, linear (swizzle via source)

    const int tid  = threadIdx.x;
    const int z    = blockIdx.z;
    const int row0 = blockIdx.y * 128;
    const int col0 = blockIdx.x * 128;
    const int wave = tid >> 6, lane = tid & 63;
    const int lr = lane & 15, lg = lane >> 4;
    const int wm = (wave >> 1) * 64, wn = (wave & 1) * 64;

    const unsigned short* Bb = Bp + (size_t)bStride * z;

    f32x4 acc[4][4] = {};

    for (int k0 = 0; k0 < K; k0 += 64) {
        // ---- stage A [128][64] bf16 ----
        if (AMODE == 0) {
            const unsigned short* A = (const unsigned short*)Ap + (size_t)aStride * z;
#pragma unroll
            for (int q = 0; q < 4; ++q) {
                int c = q * 256 + tid;
                int row = c >> 3, j = c & 7;
                const void* src = (const char*)(A + (size_t)(row0 + row) * lda + k0) + ((j ^ (row & 7)) << 4);
                gld16(src, (char*)&sh[0][0][0] + ((q * 256 + (tid & 192)) << 4));
            }
        } else {
            const float* A = (const float*)Ap + (size_t)aStride * z;
#pragma unroll
            for (int q = 0; q < 4; ++q) {
                int c = q * 256 + tid;
                int row = c >> 3, j = c & 7;
                const float* src = A + (size_t)(row0 + row) * lda + k0 + ((j ^ (row & 7)) << 3);
                float4 v0 = *(const float4*)src;
                float4 v1 = *(const float4*)(src + 4);
                uint4 p;
                p.x = (unsigned)f2bf(v0.x) | ((unsigned)f2bf(v0.y) << 16);
                p.y = (unsigned)f2bf(v0.z) | ((unsigned)f2bf(v0.w) << 16);
                p.z = (unsigned)f2bf(v1.x) | ((unsigned)f2bf(v1.y) << 16);
                p.w = (unsigned)f2bf(v1.z) | ((unsigned)f2bf(v1.w) << 16);
                *(uint4*)((char*)&sh[0][0][0] + ((size_t)c << 4)) = p;
            }
        }
        // ---- stage B [128][64] bf16 (B given as [N][K] rows) ----
#pragma unroll
        for (int q = 0; q < 4; ++q) {
            int c = q * 256 + tid;
            int row = c >> 3, j = c & 7;
            const void* src = (const char*)(Bb + (size_t)(col0 + row) * ldb + k0) + ((j ^ (row & 7)) << 4);
            gld16(src, (char*)&sh[1][0][0] + ((q * 256 + (tid & 192)) << 4));
        }
        __syncthreads();

        bf16x8 af[2][4], bfv[2][4];
#pragma unroll
        for (int s = 0; s < 2; ++s) {
#pragma unroll
            for (int i = 0; i < 4; ++i) {
                int ra = wm + i * 16 + lr;
                af[s][i]  = *(const bf16x8*)((const char*)&sh[0][0][0] + ra * 128 + ((((s << 2) | lg) ^ (ra & 7)) << 4));
                int rb = wn + i * 16 + lr;
                bfv[s][i] = *(const bf16x8*)((const char*)&sh[1][0][0] + rb * 128 + ((((s << 2) | lg) ^ (rb & 7)) << 4));
            }
        }
#pragma unroll
        for (int s = 0; s < 2; ++s)
#pragma unroll
            for (int mi = 0; mi < 4; ++mi)
#pragma unroll
                for (int ni = 0; ni < 4; ++ni)
                    acc[mi][ni] = __builtin_amdgcn_mfma_f32_16x16x32_bf16(af[s][mi], bfv[s][ni], acc[mi][ni], 0, 0, 0);
        __syncthreads();
    }

    // ---- epilogue ----
    if (EPI == 0) {
        unsigned short* C = (unsigned short*)Cp;
#pragma unroll
        for (int mi = 0; mi < 4; ++mi)
#pragma unroll
            for (int ni = 0; ni < 4; ++ni) {
                int col = col0 + wn + ni * 16 + lr;
                float bb = bias[col];
                int rowb = row0 + wm + mi * 16 + lg * 4;
#pragma unroll
                for (int v = 0; v < 4; ++v)
                    C[(size_t)(rowb + v) * ldc + col] = f2bf(acc[mi][ni][v] + bb);
            }
    } else if (EPI == 1) {
        // transposed bf16 out: C[(z*DHID + col)*S + s], 4 consecutive s packed
        unsigned short* C = (unsigned short*)Cp;
        int zz = row0 >> 11;
        int sb = (row0 & 2047) + wm;
#pragma unroll
        for (int mi = 0; mi < 4; ++mi)
#pragma unroll
            for (int ni = 0; ni < 4; ++ni) {
                int col = col0 + wn + ni * 16 + lr;
                float bb = bias[col];
                unsigned short r[4];
#pragma unroll
                for (int v = 0; v < 4; ++v) {
                    float xv = acc[mi][ni][v] + bb;
                    xv = 0.5f * xv * (1.0f + erff(xv * 0.70710678118654752f));
                    r[v] = f2bf(xv);
                }
                uint2 o;
                o.x = (unsigned)r[0] | ((unsigned)r[1] << 16);
                o.y = (unsigned)r[2] | ((unsigned)r[3] << 16);
                int s0 = sb + mi * 16 + lg * 4;
                *(uint2*)(C + ((size_t)zz * DHID + col) * S_ + s0) = o;
            }
    } else {
        float* C = (float*)Cp + (size_t)cStride * z;
        const int* mp = (EPI == 2) ? (maskp + (size_t)mStride * z) : nullptr;
#pragma unroll
        for (int mi = 0; mi < 4; ++mi)
#pragma unroll
            for (int ni = 0; ni < 4; ++ni) {
                int col = col0 + wn + ni * 16 + lr;
                int rowb = row0 + wm + mi * 16 + lg * 4;
#pragma unroll
                for (int v = 0; v < 4; ++v) {
                    float val = acc[mi][ni][v];
                    if (EPI == 2) val = val * scale + (float)mp[(size_t)(rowb + v) * ldc + col] * (-1e9f);
                    C[(size_t)(rowb + v) * ldc + col] = val;
                }
            }
    }
}

// ---------------- row softmax in place (+ optional bf16 copy) ----------------
template<bool WB>
__global__ __launch_bounds__(256)
void softmax_k(float* __restrict__ attn, unsigned short* __restrict__ attnb)
{
    const int row = blockIdx.x;
    float* p = attn + (size_t)row * S_;
    const int tid = threadIdx.x;

    float4 a = ((const float4*)p)[tid * 2];
    float4 b = ((const float4*)p)[tid * 2 + 1];

    float m = fmaxf(fmaxf(fmaxf(a.x, a.y), fmaxf(a.z, a.w)),
                    fmaxf(fmaxf(b.x, b.y), fmaxf(b.z, b.w)));
#pragma unroll
    for (int o = 32; o; o >>= 1) m = fmaxf(m, __shfl_xor(m, o));

    __shared__ float redm[4];
    __shared__ float reds[4];
    if ((tid & 63) == 0) redm[tid >> 6] = m;
    __syncthreads();
    m = fmaxf(fmaxf(redm[0], redm[1]), fmaxf(redm[2], redm[3]));

    float e[8];
    e[0] = expf(a.x - m); e[1] = expf(a.y - m); e[2] = expf(a.z - m); e[3] = expf(a.w - m);
    e[4] = expf(b.x - m); e[5] = expf(b.y - m); e[6] = expf(b.z - m); e[7] = expf(b.w - m);
    float s = e[0] + e[1] + e[2] + e[3] + e[4] + e[5] + e[6] + e[7];
#pragma unroll
    for (int o = 32; o; o >>= 1) s += __shfl_xor(s, o);
    if ((tid & 63) == 0) reds[tid >> 6] = s;
    __syncthreads();
    s = reds[0] + reds[1] + reds[2] + reds[3];
    float inv = 1.0f / s;

    float o0[8];
#pragma unroll
    for (int j = 0; j < 8; ++j) o0[j] = e[j] * inv;
    ((float4*)p)[tid * 2]     = make_float4(o0[0], o0[1], o0[2], o0[3]);
    ((float4*)p)[tid * 2 + 1] = make_float4(o0[4], o0[5], o0[6], o0[7]);

    if (WB) {
        uint4 ob;
        ob.x = (unsigned)f2bf(o0[0]) | ((unsigned)f2bf(o0[1]) << 16);
        ob.y = (unsigned)f2bf(o0[2]) | ((unsigned)f2bf(o0[3]) << 16);
        ob.z = (unsigned)f2bf(o0[4]) | ((unsigned)f2bf(o0[5]) << 16);
        ob.w = (unsigned)f2bf(o0[6]) | ((unsigned)f2bf(o0[7]) << 16);
        *(uint4*)(attnb + (size_t)row * S_ + tid * 8) = ob;
    }
}

extern "C" void kernel_launch(void* const* d_in, const int* in_sizes, int n_in,
                              void* d_out, int out_size, void* d_ws, size_t ws_size,
                              hipStream_t stream)
{
    const float* x    = (const float*)d_in[0];
    const int*   mask = (const int*)d_in[1];
    const float* Wq   = (const float*)d_in[2];
    const float* bq   = (const float*)d_in[3];
    const float* Wk   = (const float*)d_in[4];
    const float* bk   = (const float*)d_in[5];
    const float* Wv   = (const float*)d_in[6];
    const float* bv   = (const float*)d_in[7];

    float* ctx  = (float*)d_out;                       // [B,S,DHID] fp32 (written last)
    float* attn = ctx + (size_t)B_ * S_ * DHID;        // [B,S,S]    fp32

    // Qb,Kb (bf16, 2x16.78MB) in ctx region (dead until context GEMM fully overwrites it).
    unsigned short* Qb = (unsigned short*)ctx;
    unsigned short* Kb = Qb + (size_t)B_ * S_ * DATT;
    // Xb (16.78MB) + Wb (6.3MB) in attn region (dead before scores GEMM writes it).
    unsigned short* Xb = (unsigned short*)attn;
    unsigned short* Wb = Xb + (size_t)B_ * S_ * DIN;
    // WVbT (16.78MB) and optional attn-bf16 (33.55MB) in ws.
    unsigned short* WVbT  = (unsigned short*)d_ws;
    unsigned short* attnb = WVbT + (size_t)B_ * DHID * S_;
    bool planA = ws_size >= ((size_t)B_ * DHID * S_ + (size_t)B_ * S_ * S_) * 2;

    dim3 blk(256);

    xcvt_k<<<dim3(4096), blk, 0, stream>>>(x, Xb);
    wcvt_k<<<dim3(256, 3), blk, 0, stream>>>(Wq, Wk, Wv, Wb);

    // Q = Xb @ WqT' + bq -> bf16 [8192][1024]
    gemm_k<0, 0><<<dim3(8, 64, 1), blk, 0, stream>>>(
        Xb, Wb, bq, nullptr, Qb, DIN, DIN, DIN, DATT, 0, 0, 0, 0, 1.0f);
    // K = Xb @ WkT' + bk -> bf16
    gemm_k<0, 0><<<dim3(8, 64, 1), blk, 0, stream>>>(
        Xb, Wb + (size_t)DIN * DATT, bk, nullptr, Kb, DIN, DIN, DIN, DATT, 0, 0, 0, 0, 1.0f);
    // WV = gelu(Xb @ WvT' + bv) -> bf16 TRANSPOSED [B][DHID][S]
    gemm_k<0, 1><<<dim3(8, 64, 1), blk, 0, stream>>>(
        Xb, Wb + 2 * (size_t)DIN * DATT, bv, nullptr, WVbT, DIN, DIN, DIN, DHID, 0, 0, 0, 0, 1.0f);
    // scores = Q @ K^T /32 + mask*(-1e9) -> fp32 attn region
    gemm_k<0, 2><<<dim3(16, 16, 4), blk, 0, stream>>>(
        Qb, Kb, nullptr, mask, attn, DATT, DATT, DATT, S_,
        (long)S_ * DATT, (long)S_ * DATT, (long)S_ * S_, (long)S_ * S_, 0.03125f);
    // softmax rows in place (+ bf16 copy when ws allows)
    if (planA) softmax_k<true><<<dim3(B_ * S_), blk, 0, stream>>>(attn, attnb);
    else       softmax_k<false><<<dim3(B_ * S_), blk, 0, stream>>>(attn, nullptr);
    // context = attn @ WV -> fp32 (B operand = WVbT rows)
    if (planA)
        gemm_k<0, 3><<<dim3(8, 16, 4), blk, 0, stream>>>(
            attnb, WVbT, nullptr, nullptr, ctx, S_, S_, S_, DHID,
            (long)S_ * S_, (long)DHID * S_, (long)S_ * DHID, 0, 1.0f);
    else
        gemm_k<1, 3><<<dim3(8, 16, 4), blk, 0, stream>>>(
            attn, WVbT, nullptr, nullptr, ctx, S_, S_, S_, DHID,
            (long)S_ * S_, (long)DHID * S_, (long)S_ * DHID, 0, 1.0f);
}

// Round 3
// 228.507 us; speedup vs baseline: 1.5580x; 1.1632x over previous
//
#include <hip/hip_runtime.h>
#include <hip/hip_bf16.h>
#include <math.h>

#define B_   4
#define S_   2048
#define DIN  1024
#define DATT 1024
#define DHID 1024

typedef short bf16x8 __attribute__((ext_vector_type(8)));
typedef float f32x4  __attribute__((ext_vector_type(4)));

__device__ inline unsigned short f2bf(float f) {
    unsigned u = __float_as_uint(f);
    u += 0x7fffu + ((u >> 16) & 1u);
    return (unsigned short)(u >> 16);
}
__device__ inline float bf2f(unsigned u16) {
    return __uint_as_float(u16 << 16);
}
__device__ inline void gld16(const void* g, void* l) {
    __builtin_amdgcn_global_load_lds(
        (const __attribute__((address_space(1))) unsigned int*)g,
        (__attribute__((address_space(3))) unsigned int*)l, 16, 0, 0);
}

// ---------------- prep: X fp32 -> bf16 ----------------
__global__ __launch_bounds__(256)
void xcvt_k(const float* __restrict__ x, unsigned short* __restrict__ xb)
{
    int i = blockIdx.x * 256 + threadIdx.x;
    const float4* p = (const float4*)x + (size_t)i * 2;
    float4 v0 = p[0], v1 = p[1];
    uint4 o;
    o.x = (unsigned)f2bf(v0.x) | ((unsigned)f2bf(v0.y) << 16);
    o.y = (unsigned)f2bf(v0.z) | ((unsigned)f2bf(v0.w) << 16);
    o.z = (unsigned)f2bf(v1.x) | ((unsigned)f2bf(v1.y) << 16);
    o.w = (unsigned)f2bf(v1.z) | ((unsigned)f2bf(v1.w) << 16);
    ((uint4*)xb)[i] = o;
}

// ---------------- prep: W [K][N] fp32 -> Wt [N][K] bf16 ----------------
__global__ __launch_bounds__(256)
void wcvt_k(const float* __restrict__ Wq, const float* __restrict__ Wk,
            const float* __restrict__ Wv, unsigned short* __restrict__ Wt)
{
    int w = blockIdx.y;
    const float* W = (w == 0) ? Wq : ((w == 1) ? Wk : Wv);
    unsigned short* D = Wt + (size_t)w * DIN * DATT;
    int t = blockIdx.x * 256 + threadIdx.x;
    int n  = t >> 6;
    int kc = (t & 63) * 16;
    unsigned short r[16];
#pragma unroll
    for (int i = 0; i < 16; ++i) r[i] = f2bf(W[(size_t)(kc + i) * DATT + n]);
    uint4 o0, o1;
    o0.x = (unsigned)r[0] | ((unsigned)r[1] << 16);  o0.y = (unsigned)r[2] | ((unsigned)r[3] << 16);
    o0.z = (unsigned)r[4] | ((unsigned)r[5] << 16);  o0.w = (unsigned)r[6] | ((unsigned)r[7] << 16);
    o1.x = (unsigned)r[8] | ((unsigned)r[9] << 16);  o1.y = (unsigned)r[10] | ((unsigned)r[11] << 16);
    o1.z = (unsigned)r[12] | ((unsigned)r[13] << 16); o1.w = (unsigned)r[14] | ((unsigned)r[15] << 16);
    *(uint4*)(D + (size_t)n * DIN + kc)     = o0;
    *(uint4*)(D + (size_t)n * DIN + kc + 8) = o1;
}

// ---------------- GEMM: 128x128, BK=64, double-buffered single-barrier loop ----------------
// AMODE: 0 = A bf16 via global_load_lds; 1 = A fp32 cvt reg-staged
// EPI: 6 = fused QKV (Q/K bf16+bias; V gelu+bias transposed to Cp2)
//      4 = e = exp(val*scale), masked->0, bf16 out
//      5 = fp32 out * invs[row]
//      2 = fp32 out scale + mask*(-1e9)   (fallback)
//      3 = fp32 out                        (fallback)
template<int AMODE, int EPI>
__global__ __launch_bounds__(256)
void gemm_k(const void* __restrict__ Ap, const unsigned short* __restrict__ Bp,
            const float* __restrict__ b0, const float* __restrict__ b1,
            const float* __restrict__ b2, const int* __restrict__ maskp,
            void* __restrict__ Cp, void* __restrict__ Cp2,
            int K, int lda, int ldb, int ldc,
            long aStride, long bStride, long cStride, long mStride, float scale)
{
    __shared__ __align__(16) unsigned short sh[2][2][128][64];   // 64 KB

    const int tid  = threadIdx.x;
    const int z    = blockIdx.z;
    const int row0 = blockIdx.y * 128;
    const int col0 = blockIdx.x * 128;
    const int wave = tid >> 6, lane = tid & 63;
    const int lr = lane & 15, lg = lane >> 4;
    const int wm = (wave >> 1) * 64, wn = (wave & 1) * 64;

    const unsigned short* Bb = Bp + (size_t)bStride * z;

    f32x4 acc[4][4] = {};
    const int nt = K >> 6;

    auto stage = [&](int b, int k0) {
        if (AMODE == 0) {
            const unsigned short* A = (const unsigned short*)Ap + (size_t)aStride * z;
#pragma unroll
            for (int q = 0; q < 4; ++q) {
                int c = q * 256 + tid;
                int row = c >> 3, j = c & 7;
                gld16((const char*)(A + (size_t)(row0 + row) * lda + k0) + ((j ^ (row & 7)) << 4),
                      (char*)&sh[b][0][0][0] + ((q * 256 + (tid & 192)) << 4));
            }
        } else {
            const float* A = (const float*)Ap + (size_t)aStride * z;
#pragma unroll
            for (int q = 0; q < 4; ++q) {
                int c = q * 256 + tid;
                int row = c >> 3, j = c & 7;
                const float* src = A + (size_t)(row0 + row) * lda + k0 + ((j ^ (row & 7)) << 3);
                float4 v0 = *(const float4*)src;
                float4 v1 = *(const float4*)(src + 4);
                uint4 p;
                p.x = (unsigned)f2bf(v0.x) | ((unsigned)f2bf(v0.y) << 16);
                p.y = (unsigned)f2bf(v0.z) | ((unsigned)f2bf(v0.w) << 16);
                p.z = (unsigned)f2bf(v1.x) | ((unsigned)f2bf(v1.y) << 16);
                p.w = (unsigned)f2bf(v1.z) | ((unsigned)f2bf(v1.w) << 16);
                *(uint4*)((char*)&sh[b][0][0][0] + ((size_t)c << 4)) = p;
            }
        }
#pragma unroll
        for (int q = 0; q < 4; ++q) {
            int c = q * 256 + tid;
            int row = c >> 3, j = c & 7;
            gld16((const char*)(Bb + (size_t)(col0 + row) * ldb + k0) + ((j ^ (row & 7)) << 4),
                  (char*)&sh[b][1][0][0] + ((q * 256 + (tid & 192)) << 4));
        }
    };

    stage(0, 0);
    __syncthreads();
    int cur = 0;
    for (int t = 0; t < nt; ++t) {
        if (t + 1 < nt) stage(cur ^ 1, (t + 1) << 6);   // prefetch flies under compute
        const char* baseA = (const char*)&sh[cur][0][0][0];
        const char* baseB = (const char*)&sh[cur][1][0][0];
        bf16x8 af[2][4], bfv[2][4];
#pragma unroll
        for (int s = 0; s < 2; ++s)
#pragma unroll
            for (int i = 0; i < 4; ++i) {
                int ra = wm + i * 16 + lr;
                af[s][i]  = *(const bf16x8*)(baseA + ra * 128 + ((((s << 2) | lg) ^ (ra & 7)) << 4));
                int rb = wn + i * 16 + lr;
                bfv[s][i] = *(const bf16x8*)(baseB + rb * 128 + ((((s << 2) | lg) ^ (rb & 7)) << 4));
            }
#pragma unroll
        for (int s = 0; s < 2; ++s)
#pragma unroll
            for (int mi = 0; mi < 4; ++mi)
#pragma unroll
                for (int ni = 0; ni < 4; ++ni)
                    acc[mi][ni] = __builtin_amdgcn_mfma_f32_16x16x32_bf16(af[s][mi], bfv[s][ni], acc[mi][ni], 0, 0, 0);
        if (t + 1 < nt) __syncthreads();
        cur ^= 1;
    }

    // ---- epilogue ----
    if (EPI == 6) {
        int w = col0 >> 10;
        int cb = (col0 & 1023) + wn;
        if (w < 2) {
            unsigned short* C = (unsigned short*)Cp + (size_t)w * ((size_t)B_ * S_ * DATT);
            const float* bias = w ? b1 : b0;
#pragma unroll
            for (int mi = 0; mi < 4; ++mi)
#pragma unroll
                for (int ni = 0; ni < 4; ++ni) {
                    int col = cb + ni * 16 + lr;
                    float bb = bias[col];
                    int rowb = row0 + wm + mi * 16 + lg * 4;
#pragma unroll
                    for (int v = 0; v < 4; ++v)
                        C[(size_t)(rowb + v) * DATT + col] = f2bf(acc[mi][ni][v] + bb);
                }
        } else {
            unsigned short* C = (unsigned short*)Cp2;
            int zz = row0 >> 11;
            int sb = (row0 & 2047) + wm;
#pragma unroll
            for (int mi = 0; mi < 4; ++mi)
#pragma unroll
                for (int ni = 0; ni < 4; ++ni) {
                    int col = cb + ni * 16 + lr;
                    float bb = b2[col];
                    unsigned short r[4];
#pragma unroll
                    for (int v = 0; v < 4; ++v) {
                        float xv = acc[mi][ni][v] + bb;
                        xv = 0.5f * xv * (1.0f + erff(xv * 0.70710678118654752f));
                        r[v] = f2bf(xv);
                    }
                    uint2 o;
                    o.x = (unsigned)r[0] | ((unsigned)r[1] << 16);
                    o.y = (unsigned)r[2] | ((unsigned)r[3] << 16);
                    *(uint2*)(C + ((size_t)zz * DHID + col) * S_ + sb + mi * 16 + lg * 4) = o;
                }
        }
    } else if (EPI == 4) {
        unsigned short* C = (unsigned short*)Cp + (size_t)cStride * z;
        const int* mp = maskp + (size_t)mStride * z;
#pragma unroll
        for (int mi = 0; mi < 4; ++mi)
#pragma unroll
            for (int ni = 0; ni < 4; ++ni) {
                int col = col0 + wn + ni * 16 + lr;
                int rowb = row0 + wm + mi * 16 + lg * 4;
#pragma unroll
                for (int v = 0; v < 4; ++v) {
                    float sv = acc[mi][ni][v] * scale;
                    int mk = mp[(size_t)(rowb + v) * ldc + col];
                    float ev = mk ? 0.0f : __expf(sv);
                    C[(size_t)(rowb + v) * ldc + col] = f2bf(ev);
                }
            }
    } else if (EPI == 5) {
        float* C = (float*)Cp + (size_t)cStride * z;
        const float* invs = b0 + (size_t)z * S_;
#pragma unroll
        for (int mi = 0; mi < 4; ++mi)
#pragma unroll
            for (int ni = 0; ni < 4; ++ni) {
                int col = col0 + wn + ni * 16 + lr;
                int rowb = row0 + wm + mi * 16 + lg * 4;
#pragma unroll
                for (int v = 0; v < 4; ++v)
                    C[(size_t)(rowb + v) * ldc + col] = acc[mi][ni][v] * invs[rowb + v];
            }
    } else {
        float* C = (float*)Cp + (size_t)cStride * z;
        const int* mp = (EPI == 2) ? (maskp + (size_t)mStride * z) : nullptr;
#pragma unroll
        for (int mi = 0; mi < 4; ++mi)
#pragma unroll
            for (int ni = 0; ni < 4; ++ni) {
                int col = col0 + wn + ni * 16 + lr;
                int rowb = row0 + wm + mi * 16 + lg * 4;
#pragma unroll
                for (int v = 0; v < 4; ++v) {
                    float val = acc[mi][ni][v];
                    if (EPI == 2) val = val * scale + (float)mp[(size_t)(rowb + v) * ldc + col] * (-1e9f);
                    C[(size_t)(rowb + v) * ldc + col] = val;
                }
            }
    }
}

// ---------------- rowsum / normalize over e (bf16 rows of 2048) ----------------
template<bool WRITEATTN>
__global__ __launch_bounds__(256)
void rownorm_k(const unsigned short* __restrict__ e, float* __restrict__ attn,
               float* __restrict__ invs)
{
    const int row = blockIdx.x;
    const int tid = threadIdx.x;
    uint4 u = ((const uint4*)(e + (size_t)row * S_))[tid];
    float f[8];
    f[0] = bf2f(u.x & 0xffffu); f[1] = bf2f(u.x >> 16);
    f[2] = bf2f(u.y & 0xffffu); f[3] = bf2f(u.y >> 16);
    f[4] = bf2f(u.z & 0xffffu); f[5] = bf2f(u.z >> 16);
    f[6] = bf2f(u.w & 0xffffu); f[7] = bf2f(u.w >> 16);
    float s = ((f[0] + f[1]) + (f[2] + f[3])) + ((f[4] + f[5]) + (f[6] + f[7]));
#pragma unroll
    for (int o = 32; o; o >>= 1) s += __shfl_xor(s, o);
    __shared__ float red[4];
    if ((tid & 63) == 0) red[tid >> 6] = s;
    __syncthreads();
    s = (red[0] + red[1]) + (red[2] + red[3]);
    float inv = 1.0f / s;
    if (WRITEATTN) {
        float* p = attn + (size_t)row * S_;
        ((float4*)p)[tid * 2]     = make_float4(f[0] * inv, f[1] * inv, f[2] * inv, f[3] * inv);
        ((float4*)p)[tid * 2 + 1] = make_float4(f[4] * inv, f[5] * inv, f[6] * inv, f[7] * inv);
    } else {
        if (tid == 0) invs[row] = inv;
    }
}

// ---------------- fallback row softmax in place ----------------
__global__ __launch_bounds__(256)
void softmax_k(float* __restrict__ attn)
{
    const int row = blockIdx.x;
    float* p = attn + (size_t)row * S_;
    const int tid = threadIdx.x;
    float4 a = ((const float4*)p)[tid * 2];
    float4 b = ((const float4*)p)[tid * 2 + 1];
    float m = fmaxf(fmaxf(fmaxf(a.x, a.y), fmaxf(a.z, a.w)),
                    fmaxf(fmaxf(b.x, b.y), fmaxf(b.z, b.w)));
#pragma unroll
    for (int o = 32; o; o >>= 1) m = fmaxf(m, __shfl_xor(m, o));
    __shared__ float redm[4];
    __shared__ float reds[4];
    if ((tid & 63) == 0) redm[tid >> 6] = m;
    __syncthreads();
    m = fmaxf(fmaxf(redm[0], redm[1]), fmaxf(redm[2], redm[3]));
    float e[8];
    e[0] = expf(a.x - m); e[1] = expf(a.y - m); e[2] = expf(a.z - m); e[3] = expf(a.w - m);
    e[4] = expf(b.x - m); e[5] = expf(b.y - m); e[6] = expf(b.z - m); e[7] = expf(b.w - m);
    float s = e[0] + e[1] + e[2] + e[3] + e[4] + e[5] + e[6] + e[7];
#pragma unroll
    for (int o = 32; o; o >>= 1) s += __shfl_xor(s, o);
    if ((tid & 63) == 0) reds[tid >> 6] = s;
    __syncthreads();
    s = reds[0] + reds[1] + reds[2] + reds[3];
    float inv = 1.0f / s;
    ((float4*)p)[tid * 2]     = make_float4(e[0] * inv, e[1] * inv, e[2] * inv, e[3] * inv);
    ((float4*)p)[tid * 2 + 1] = make_float4(e[4] * inv, e[5] * inv, e[6] * inv, e[7] * inv);
}

extern "C" void kernel_launch(void* const* d_in, const int* in_sizes, int n_in,
                              void* d_out, int out_size, void* d_ws, size_t ws_size,
                              hipStream_t stream)
{
    const float* x    = (const float*)d_in[0];
    const int*   mask = (const int*)d_in[1];
    const float* Wq   = (const float*)d_in[2];
    const float* bq   = (const float*)d_in[3];
    const float* Wk   = (const float*)d_in[4];
    const float* bk   = (const float*)d_in[5];
    const float* Wv   = (const float*)d_in[6];
    const float* bv   = (const float*)d_in[7];

    float* ctx  = (float*)d_out;                       // [B,S,DHID] fp32
    float* attn = ctx + (size_t)B_ * S_ * DHID;        // [B,S,S]    fp32

    // ctx region: Qb + Kb (bf16, exactly 33.55 MB) — dead after scores GEMM.
    unsigned short* Qb = (unsigned short*)ctx;
    unsigned short* Kb = Qb + (size_t)B_ * S_ * DATT;
    // attn region (67.1 MB): Xb (16.8) + Wb (6.3) + WVbT (16.8) — all dead before the
    // final attn-normalize pass overwrites this region.
    unsigned short* Xb   = (unsigned short*)attn;
    unsigned short* Wb   = Xb + (size_t)B_ * S_ * DIN;
    unsigned short* WVbT = Wb + (size_t)3 * DIN * DATT;

    const size_t eElems = (size_t)B_ * S_ * S_;
    bool fast = ws_size >= eElems * 2 + (size_t)B_ * S_ * 4 + 256;

    dim3 blk(256);

    xcvt_k<<<dim3(4096), blk, 0, stream>>>(x, Xb);
    wcvt_k<<<dim3(256, 3), blk, 0, stream>>>(Wq, Wk, Wv, Wb);

    if (fast) {
        unsigned short* e    = (unsigned short*)d_ws;              // 33.55 MB
        float*          invs = (float*)(e + eElems);               // 32 KB

        // fused QKV: [8192,3072] = Xb @ Wb^T(+bias); V third gets gelu+transpose
        gemm_k<0, 6><<<dim3(24, 64, 1), blk, 0, stream>>>(
            Xb, Wb, bq, bk, bv, nullptr, Qb, WVbT,
            DIN, DIN, DIN, 0, 0, 0, 0, 0, 1.0f);
        // e = exp(QK^T/32), masked -> 0, bf16
        gemm_k<0, 4><<<dim3(16, 16, 4), blk, 0, stream>>>(
            Qb, Kb, nullptr, nullptr, nullptr, mask, e, nullptr,
            DATT, DATT, DATT, S_,
            (long)S_ * DATT, (long)S_ * DATT, (long)S_ * S_, (long)S_ * S_, 0.03125f);
        // row sums -> invs
        rownorm_k<false><<<dim3(B_ * S_), blk, 0, stream>>>(e, nullptr, invs);
        // ctx = (e @ WV) * inv_rowsum  (overwrites Qb/Kb region)
        gemm_k<0, 5><<<dim3(8, 16, 4), blk, 0, stream>>>(
            e, WVbT, invs, nullptr, nullptr, nullptr, ctx, nullptr,
            S_, S_, S_, DHID,
            (long)S_ * S_, (long)DHID * S_, (long)S_ * DHID, 0, 1.0f);
        // attn = e * inv_rowsum (fp32) — LAST, clobbers Xb/Wb/WVbT
        rownorm_k<true><<<dim3(B_ * S_), blk, 0, stream>>>(e, attn, nullptr);
    } else {
        // fallback: R2-proven path; WVbT must live in ws (16.78 MB)
        unsigned short* WVw = (unsigned short*)d_ws;
        gemm_k<0, 6><<<dim3(24, 64, 1), blk, 0, stream>>>(
            Xb, Wb, bq, bk, bv, nullptr, Qb, WVw,
            DIN, DIN, DIN, 0, 0, 0, 0, 0, 1.0f);
        gemm_k<0, 2><<<dim3(16, 16, 4), blk, 0, stream>>>(
            Qb, Kb, nullptr, nullptr, nullptr, mask, attn, nullptr,
            DATT, DATT, DATT, S_,
            (long)S_ * DATT, (long)S_ * DATT, (long)S_ * S_, (long)S_ * S_, 0.03125f);
        softmax_k<<<dim3(B_ * S_), blk, 0, stream>>>(attn);
        gemm_k<1, 3><<<dim3(8, 16, 4), blk, 0, stream>>>(
            attn, WVw, nullptr, nullptr, nullptr, nullptr, ctx, nullptr,
            S_, S_, S_, DHID,
            (long)S_ * S_, (long)DHID * S_, (long)S_ * DHID, 0, 1.0f);
    }
}